// Round 13
// baseline (294.436 us; speedup 1.0000x reference)
//
#include <hip/hip_runtime.h>
#include <hip/hip_bf16.h>

#define NA 100000
#define NB 50000
#define EAA 1600000
#define EAB 800000
#define EBB 800000

#define NBKAA 782   // ceil(NA/128)
#define NBKB  391   // ceil(NB/128)
#define BKA 200     // blocks for aa set (8000 edges each)
#define BKB 100     // blocks for ab/bb sets (8000 edges each)
#define DCAP 4096   // kD staging capacity

#define GF2A 782    // ceil(NA/128) fin row-blocks, A (4 waves x 32 rows)
#define GF2B 391    // ceil(NB/128) fin row-blocks, B

typedef __hip_bfloat16 bf16;
typedef __attribute__((ext_vector_type(8))) short bf16x8;
typedef __attribute__((ext_vector_type(4))) float f32x4;

__device__ __forceinline__ float u2f(unsigned short u) {
  union { unsigned int i; float f; } x; x.i = ((unsigned int)u) << 16; return x.f;
}
__device__ __forceinline__ unsigned short f2u(float f) {
  __hip_bfloat16 h = __float2bfloat16(f);
  return *reinterpret_cast<unsigned short*>(&h);
}
__device__ __forceinline__ short f2bs(float f) {
  __hip_bfloat16 h = __float2bfloat16(f);
  return *reinterpret_cast<short*>(&h);
}
__device__ __forceinline__ float fast_sigmoid(float z) {
  return 1.f / (1.f + __expf(-z));
}
__device__ __forceinline__ float fast_tanh(float z) {
  z = fminf(fmaxf(z, -15.f), 15.f);
  float t = __expf(2.f * z);
  return (t - 1.f) / (t + 1.f);
}

// =============== CSR build: atomic-free counting sort ===============
__global__ __launch_bounds__(256) void kA_bin(
    const int* __restrict__ d1, const int* __restrict__ d2, const int* __restrict__ d3,
    int* __restrict__ binAA, int* __restrict__ binAB, int* __restrict__ binBB) {
  __shared__ int h[1024];
  int blk = blockIdx.x;
  const int* dst; int* out; int e0, nbk;
  if (blk < BKA)            { dst = d1; out = binAA + blk * NBKAA; e0 = blk * 8000; nbk = NBKAA; }
  else if (blk < BKA + BKB) { int k = blk - BKA; dst = d2; out = binAB + k * NBKB; e0 = k * 8000; nbk = NBKB; }
  else                      { int k = blk - BKA - BKB; dst = d3; out = binBB + k * NBKB; e0 = k * 8000; nbk = NBKB; }
  for (int i = threadIdx.x; i < nbk; i += 256) h[i] = 0;
  __syncthreads();
  for (int i = threadIdx.x; i < 8000; i += 256) atomicAdd(&h[dst[e0 + i] >> 7], 1);
  __syncthreads();
  for (int i = threadIdx.x; i < nbk; i += 256) out[i] = h[i];
}

__global__ __launch_bounds__(256) void kB1(
    int* __restrict__ binAA, int* __restrict__ binAB, int* __restrict__ binBB,
    int* __restrict__ totAA, int* __restrict__ totAB, int* __restrict__ totBB) {
  int wave = threadIdx.x >> 6, lane = threadIdx.x & 63;
  int wid = blockIdx.x * 4 + wave;
  int* bin; int* tot; int b, nblk, nbk;
  if (wid < NBKAA)              { bin = binAA; tot = totAA; b = wid; nblk = BKA; nbk = NBKAA; }
  else if (wid < NBKAA + NBKB)  { bin = binAB; tot = totAB; b = wid - NBKAA; nblk = BKB; nbk = NBKB; }
  else                          { bin = binBB; tot = totBB; b = wid - NBKAA - NBKB; nblk = BKB; nbk = NBKB; }
  int C = (nblk + 63) / 64;  // 4 for aa, 2 for ab/bb
  int vals[4]; int s = 0;
  for (int j = 0; j < C; ++j) { int k = lane * C + j; vals[j] = (k < nblk) ? bin[k * nbk + b] : 0; s += vals[j]; }
  int pre = s;
  for (int o = 1; o < 64; o <<= 1) { int x = __shfl_up(pre, o); if (lane >= o) pre += x; }
  int run = pre - s;
  for (int j = 0; j < C; ++j) { int k = lane * C + j; if (k < nblk) { int v = vals[j]; bin[k * nbk + b] = run; run += v; } }
  if (lane == 63) tot[b] = pre;
}

__global__ __launch_bounds__(256) void kB2(
    const int* __restrict__ totAA, const int* __restrict__ totAB, const int* __restrict__ totBB,
    int* __restrict__ bsAA, int* __restrict__ bsAB, int* __restrict__ bsBB) {
  __shared__ int part[256];
  int set = blockIdx.x; const int* tot; int* bs; int nbk;
  if (set == 0)      { tot = totAA; bs = bsAA; nbk = NBKAA; }
  else if (set == 1) { tot = totAB; bs = bsAB; nbk = NBKB; }
  else               { tot = totBB; bs = bsBB; nbk = NBKB; }
  int t = threadIdx.x;
  int v[4]; int s = 0;
  #pragma unroll
  for (int j = 0; j < 4; ++j) { int k = t * 4 + j; v[j] = (k < nbk) ? tot[k] : 0; s += v[j]; }
  part[t] = s;
  __syncthreads();
  for (int o = 1; o < 256; o <<= 1) {
    int x = (t >= o) ? part[t - o] : 0;
    __syncthreads();
    part[t] += x;
    __syncthreads();
  }
  int run = part[t] - s;
  #pragma unroll
  for (int j = 0; j < 4; ++j) { int k = t * 4 + j; if (k < nbk) { bs[k] = run; run += v[j]; } }
  if (t == 255) bs[nbk] = part[255];
}

__global__ __launch_bounds__(256) void kC_scatter(
    const int* __restrict__ s1, const int* __restrict__ d1,
    const int* __restrict__ s2, const int* __restrict__ d2,
    const int* __restrict__ s3, const int* __restrict__ d3,
    const int* __restrict__ binAA, const int* __restrict__ binAB, const int* __restrict__ binBB,
    const int* __restrict__ bsAA, const int* __restrict__ bsAB, const int* __restrict__ bsBB,
    int* __restrict__ pkAA, int* __restrict__ pkAB, int* __restrict__ pkBB) {
  __shared__ int baseL[1024];
  __shared__ int run[1024];
  int blk = blockIdx.x;
  const int* src; const int* dst; const int* bin; const int* bs; int* pk; int e0, nbk, bofs;
  if (blk < BKA)            { src = s1; dst = d1; bin = binAA; bs = bsAA; pk = pkAA; e0 = blk * 8000; nbk = NBKAA; bofs = blk * NBKAA; }
  else if (blk < BKA + BKB) { int k = blk - BKA; src = s2; dst = d2; bin = binAB; bs = bsAB; pk = pkAB; e0 = k * 8000; nbk = NBKB; bofs = k * NBKB; }
  else                      { int k = blk - BKA - BKB; src = s3; dst = d3; bin = binBB; bs = bsBB; pk = pkBB; e0 = k * 8000; nbk = NBKB; bofs = k * NBKB; }
  for (int i = threadIdx.x; i < nbk; i += 256) { baseL[i] = bs[i] + bin[bofs + i]; run[i] = 0; }
  __syncthreads();
  for (int i = threadIdx.x; i < 8000; i += 256) {
    int d = dst[e0 + i];
    int b = d >> 7;
    int off = atomicAdd(&run[b], 1);
    pk[baseL[b] + off] = src[e0 + i] | ((d & 127) << 24);
  }
}

__global__ __launch_bounds__(256) void kD_nodesort(
    const int* __restrict__ pkAA, const int* __restrict__ pkAB, const int* __restrict__ pkBB,
    const int* __restrict__ bsAA, const int* __restrict__ bsAB, const int* __restrict__ bsBB,
    int* __restrict__ colAA, int* __restrict__ colAB, int* __restrict__ colBB,
    int* __restrict__ stAA, int* __restrict__ ctAA,
    int* __restrict__ stAB, int* __restrict__ ctAB,
    int* __restrict__ stBB, int* __restrict__ ctBB) {
  __shared__ int hist[128], nodeOff[129], run[128];
  __shared__ int stage[DCAP];
  int wid = blockIdx.x;
  const int* pk; const int* bs; int* col; int* stn; int* ctn; int b, N;
  if (wid < NBKAA)             { pk = pkAA; bs = bsAA; col = colAA; stn = stAA; ctn = ctAA; b = wid; N = NA; }
  else if (wid < NBKAA + NBKB) { pk = pkAB; bs = bsAB; col = colAB; stn = stAB; ctn = ctAB; b = wid - NBKAA; N = NB; }
  else                         { pk = pkBB; bs = bsBB; col = colBB; stn = stBB; ctn = ctBB; b = wid - NBKAA - NBKB; N = NB; }
  int node0 = b * 128;
  int base = bs[b], cntB = bs[b + 1] - base;
  int t = threadIdx.x;
  if (t < 128) hist[t] = 0;
  __syncthreads();
  for (int i = t; i < cntB; i += 256) atomicAdd(&hist[pk[base + i] >> 24], 1);
  __syncthreads();
  if (t < 64) {
    int v0 = hist[2 * t], v1 = hist[2 * t + 1];
    int s = v0 + v1; int pre = s;
    for (int o = 1; o < 64; o <<= 1) { int x = __shfl_up(pre, o); if (t >= o) pre += x; }
    int ex = pre - s;
    nodeOff[2 * t] = ex; nodeOff[2 * t + 1] = ex + v0;
    if (t == 63) nodeOff[128] = pre;
    run[2 * t] = 0; run[2 * t + 1] = 0;
  }
  __syncthreads();
  if (t < 128) {
    int n = node0 + t;
    if (n < N) { ctn[n] = hist[t]; stn[n] = base + nodeOff[t]; }
  }
  if (cntB <= DCAP) {
    for (int i = t; i < cntB; i += 256) {
      int e = pk[base + i]; int ln = e >> 24;
      int off = atomicAdd(&run[ln], 1);
      stage[nodeOff[ln] + off] = e & 0xFFFFFF;
    }
    __syncthreads();
    for (int i = t; i < cntB; i += 256) col[base + i] = stage[i];
  } else {
    for (int i = t; i < cntB; i += 256) {
      int e = pk[base + i]; int ln = e >> 24;
      int off = atomicAdd(&run[ln], 1);
      col[base + nodeOff[ln] + off] = e & 0xFFFFFF;
    }
  }
}

// ---------------- cast x (f32) -> bf16 ----------------
__global__ __launch_bounds__(256) void k_cast2(const float* __restrict__ xa, const float* __restrict__ xb,
                                               bf16* __restrict__ ya, bf16* __restrict__ yb) {
  int i = blockIdx.x * 256 + threadIdx.x;
  const float* x; bf16* y; int base;
  if (i < 800000)       { x = xa; y = ya; base = i * 4; }
  else if (i < 1200000) { x = xb; y = yb; base = (i - 800000) * 4; }
  else return;
  float4 v = *(const float4*)(x + base);
  ushort4 o; o.x = f2u(v.x); o.y = f2u(v.y); o.z = f2u(v.z); o.w = f2u(v.w);
  *(ushort4*)(y + base) = o;
}

// ---- kW1: phase-1 intermediates M[term][g] = L @ R  (20 blocks) ----
__global__ __launch_bounds__(256) void kW1(
    const float* __restrict__ lin_w, const float* __restrict__ wl, const float* __restrict__ wr,
    float* __restrict__ Mbuf) {
  __shared__ float Ls[32][64];
  __shared__ float Rs[64][64];
  int id = blockIdx.x, term = id >> 2, g = id & 3;
  const float* L = lin_w + ((size_t)g * 2 + (term >= 3 ? 1 : 0)) * 2048;
  const float* R1; const float* R2 = nullptr;
  switch (term) {
    case 0: R1 = wl + ((size_t)(g * 2) * 3 + 0) * 4096; break;
    case 1: R1 = wr + ((size_t)(g * 2) * 3 + 0) * 4096; break;
    case 2: R1 = wl + ((size_t)(g * 2) * 3 + 1) * 4096; break;
    case 3: R1 = wl + ((size_t)(g * 2) * 3 + 2) * 4096; break;
    default: R1 = wr + ((size_t)(g * 2) * 3 + 1) * 4096; R2 = wr + ((size_t)(g * 2) * 3 + 2) * 4096; break;
  }
  for (int i = threadIdx.x; i < 2048; i += 256) Ls[i >> 6][i & 63] = L[i];
  for (int i = threadIdx.x; i < 4096; i += 256) Rs[i >> 6][i & 63] = R2 ? (R1[i] + R2[i]) : R1[i];
  __syncthreads();
  int c = threadIdx.x & 63, rq = threadIdx.x >> 6;
  float acc[8] = {0, 0, 0, 0, 0, 0, 0, 0};
  for (int k = 0; k < 64; ++k) {
    float rv = Rs[k][c];
    #pragma unroll
    for (int i = 0; i < 8; ++i) acc[i] += Ls[rq * 8 + i][k] * rv;
  }
  #pragma unroll
  for (int i = 0; i < 8; ++i)
    Mbuf[(size_t)(term * 4 + g) * 2048 + (rq * 8 + i) * 64 + c] = acc[i];
}

// ---- kW2: 36 output mats (bf16 MFMA B-fragments) + 4 bias blocks ----
__global__ __launch_bounds__(256) void kW2(
    const float* __restrict__ Mbuf, const float* __restrict__ wl, const float* __restrict__ wr,
    const float* __restrict__ cbv, const float* __restrict__ lin_b,
    bf16* __restrict__ Wfrag, float* __restrict__ Bv) {
  __shared__ float Ps[2][32][65];
  __shared__ float Ws[2][64][64];
  int blk = blockIdx.x;
  if (blk >= 36) {
    int g = blk - 36;
    if (threadIdx.x < 64) {
      int c = threadIdx.x;
      const float* b00 = cbv + (size_t)((g * 2 + 0) * 3 + 0) * 64;
      const float* b10 = cbv + (size_t)((g * 2 + 0) * 3 + 1) * 64;
      const float* b20 = cbv + (size_t)((g * 2 + 0) * 3 + 2) * 64;
      const float* b01 = cbv + (size_t)((g * 2 + 1) * 3 + 0) * 64;
      const float* b11 = cbv + (size_t)((g * 2 + 1) * 3 + 1) * 64;
      const float* b21 = cbv + (size_t)((g * 2 + 1) * 3 + 2) * 64;
      const float* wl01 = wl + (size_t)((g * 2 + 1) * 3 + 0) * 4096;
      const float* wl11 = wl + (size_t)((g * 2 + 1) * 3 + 1) * 4096;
      const float* wl21 = wl + (size_t)((g * 2 + 1) * 3 + 2) * 4096;
      const float* wr01 = wr + (size_t)((g * 2 + 1) * 3 + 0) * 4096;
      const float* wr11 = wr + (size_t)((g * 2 + 1) * 3 + 1) * 4096;
      const float* wr21 = wr + (size_t)((g * 2 + 1) * 3 + 2) * 4096;
      float s_maa = 0.f, s_ca = 0.f, s_mab = 0.f, s_mbb = 0.f, s_cb = 0.f;
      for (int k = 0; k < 64; ++k) {
        float v0 = b00[k], vb = b10[k] + b20[k];
        s_maa += v0 * wl01[k * 64 + c];
        s_ca  += v0 * wr01[k * 64 + c];
        s_mab += v0 * wl11[k * 64 + c];
        s_mbb += vb * wl21[k * 64 + c];
        s_cb  += vb * (wr11[k * 64 + c] + wr21[k * 64 + c]);
      }
      Bv[(g * 5 + 0) * 64 + c] = s_maa;
      Bv[(g * 5 + 1) * 64 + c] = s_ca + b01[c] + lin_b[(g * 2 + 0) * 64 + c];
      Bv[(g * 5 + 2) * 64 + c] = s_mab;
      Bv[(g * 5 + 3) * 64 + c] = s_mbb;
      Bv[(g * 5 + 4) * 64 + c] = s_cb + b11[c] + b21[c] + lin_b[(g * 2 + 1) * 64 + c];
    }
    return;
  }
  int mat = blk, g, m;
  if (blk < 12) { g = blk / 3; m = blk % 3; }
  else          { g = (blk - 12) / 6; m = (blk - 12) % 6 + 3; }
  const float* wl01 = wl + (size_t)((g * 2 + 1) * 3 + 0) * 4096;
  const float* wl11 = wl + (size_t)((g * 2 + 1) * 3 + 1) * 4096;
  const float* wl21 = wl + (size_t)((g * 2 + 1) * 3 + 2) * 4096;
  const float* wr01 = wr + (size_t)((g * 2 + 1) * 3 + 0) * 4096;
  const float* wr11 = wr + (size_t)((g * 2 + 1) * 3 + 1) * 4096;
  const float* wr21 = wr + (size_t)((g * 2 + 1) * 3 + 2) * 4096;
  int   p1t, p2t = -1;
  const float *w1a = nullptr, *w1b = nullptr, *w2a = nullptr, *w2b = nullptr;
  switch (m) {
    case 0: p1t = 0; w1a = wl01; break;
    case 1: p1t = 1; w1a = wl01; p2t = 0; w2a = wr01; break;
    case 2: p1t = 1; w1a = wr01; break;
    case 3: p1t = 0; w1a = wl11; break;
    case 4: p1t = 1; w1a = wl11; p2t = 2; w2a = wr11; w2b = wr21; break;
    case 5: p1t = 2; w1a = wl21; break;
    case 6: p1t = 3; w1a = wl21; break;
    case 7: p1t = 3; w1a = wr11; w1b = wr21; p2t = 4; w2a = wl21; break;
    default: p1t = 4; w1a = wr11; w1b = wr21; break;
  }
  int nprod = (p2t >= 0) ? 2 : 1;
  for (int i = threadIdx.x; i < 2048; i += 256) Ps[0][i >> 6][i & 63] = Mbuf[(size_t)(p1t * 4 + g) * 2048 + i];
  for (int i = threadIdx.x; i < 4096; i += 256) Ws[0][i >> 6][i & 63] = w1b ? (w1a[i] + w1b[i]) : w1a[i];
  if (nprod == 2) {
    for (int i = threadIdx.x; i < 2048; i += 256) Ps[1][i >> 6][i & 63] = Mbuf[(size_t)(p2t * 4 + g) * 2048 + i];
    for (int i = threadIdx.x; i < 4096; i += 256) Ws[1][i >> 6][i & 63] = w2b ? (w2a[i] + w2b[i]) : w2a[i];
  }
  __syncthreads();
  int nt = threadIdx.x >> 6, lane = threadIdx.x & 63;
  int c = nt * 16 + (lane & 15), kb = (lane >> 4) * 8;
  float acc[8] = {0, 0, 0, 0, 0, 0, 0, 0};
  for (int k = 0; k < 64; ++k) {
    float w1v = Ws[0][k][c];
    #pragma unroll
    for (int j = 0; j < 8; ++j) acc[j] += Ps[0][kb + j][k] * w1v;
  }
  if (nprod == 2) {
    for (int k = 0; k < 64; ++k) {
      float w2v = Ws[1][k][c];
      #pragma unroll
      for (int j = 0; j < 8; ++j) acc[j] += Ps[1][kb + j][k] * w2v;
    }
  }
  bf16x8 v;
  #pragma unroll
  for (int j = 0; j < 8; ++j) v[j] = f2bs(acc[j]);
  *(bf16x8*)(Wfrag + ((size_t)(mat * 4 + nt) * 64 + lane) * 8) = v;
}

// ---- pass-1 32-ch mean agg: P=A_aa(xa), Q=A_ab(xa), R=A_bb(xb); 8 edge-slots/wave ----
__global__ __launch_bounds__(256) void k_aggP1(
    const bf16* __restrict__ xa, const bf16* __restrict__ xb,
    bf16* __restrict__ P, bf16* __restrict__ Q, bf16* __restrict__ R,
    const int* __restrict__ st_aa, const int* __restrict__ ct_aa, const int* __restrict__ col_aa,
    const int* __restrict__ st_ab, const int* __restrict__ ct_ab, const int* __restrict__ col_ab,
    const int* __restrict__ st_bb, const int* __restrict__ ct_bb, const int* __restrict__ col_bb) {
  int b = blockIdx.x;
  const bf16* src; bf16* dst; const int* start; const int* cnt; const int* col; int n0;
  if (b < 25000)      { src = xa; dst = P; start = st_aa; cnt = ct_aa; col = col_aa; n0 = b * 4; }
  else if (b < 37500) { src = xa; dst = Q; start = st_ab; cnt = ct_ab; col = col_ab; n0 = (b - 25000) * 4; }
  else                { src = xb; dst = R; start = st_bb; cnt = ct_bb; col = col_bb; n0 = (b - 37500) * 4; }
  int wave = threadIdx.x >> 6, lane = threadIdx.x & 63;
  int n = n0 + wave;
  int e8 = lane >> 3, c8 = lane & 7;
  unsigned coff = (unsigned)(c8 << 3);
  int st = start[n];
  int deg = cnt[n];
  float s0 = 0.f, s1 = 0.f, s2 = 0.f, s3 = 0.f;
  #pragma unroll 2
  for (int e = e8; e < deg; e += 8) {
    int i = col[st + e];
    ushort4 v = *(const ushort4*)((const char*)src + (((unsigned)i << 6) + coff));
    s0 += u2f(v.x); s1 += u2f(v.y); s2 += u2f(v.z); s3 += u2f(v.w);
  }
  s0 += __shfl_xor(s0, 8);  s1 += __shfl_xor(s1, 8);  s2 += __shfl_xor(s2, 8);  s3 += __shfl_xor(s3, 8);
  s0 += __shfl_xor(s0, 16); s1 += __shfl_xor(s1, 16); s2 += __shfl_xor(s2, 16); s3 += __shfl_xor(s3, 16);
  s0 += __shfl_xor(s0, 32); s1 += __shfl_xor(s1, 32); s2 += __shfl_xor(s2, 32); s3 += __shfl_xor(s3, 32);
  if (e8 == 0) {
    float inv = 1.f / (float)(deg > 1 ? deg : 1);
    ushort4 o; o.x = f2u(s0 * inv); o.y = f2u(s1 * inv); o.z = f2u(s2 * inv); o.w = f2u(s3 * inv);
    *(ushort4*)((char*)dst + (((unsigned)n << 6) + coff)) = o;
  }
}

// ---- pass-2: P2=A_aa(P), Q2=A_ab(P), S=A_bb(Q) & T=A_bb(R) fused; 8 edge-slots/wave ----
__global__ __launch_bounds__(256) void k_aggP2(
    const bf16* __restrict__ P, const bf16* __restrict__ Q, const bf16* __restrict__ R,
    bf16* __restrict__ P2, bf16* __restrict__ Q2, bf16* __restrict__ S, bf16* __restrict__ T,
    const int* __restrict__ st_aa, const int* __restrict__ ct_aa, const int* __restrict__ col_aa,
    const int* __restrict__ st_ab, const int* __restrict__ ct_ab, const int* __restrict__ col_ab,
    const int* __restrict__ st_bb, const int* __restrict__ ct_bb, const int* __restrict__ col_bb) {
  int b = blockIdx.x;
  int wave = threadIdx.x >> 6, lane = threadIdx.x & 63;
  int e8 = lane >> 3, c8 = lane & 7;
  unsigned coff = (unsigned)(c8 << 3);
  if (b < 37500) {
    const bf16* src; bf16* dst; const int* start; const int* cnt; const int* col; int n0;
    if (b < 25000) { src = P; dst = P2; start = st_aa; cnt = ct_aa; col = col_aa; n0 = b * 4; }
    else           { src = P; dst = Q2; start = st_ab; cnt = ct_ab; col = col_ab; n0 = (b - 25000) * 4; }
    int n = n0 + wave;
    int st = start[n];
    int deg = cnt[n];
    float s0 = 0.f, s1 = 0.f, s2 = 0.f, s3 = 0.f;
    #pragma unroll 2
    for (int e = e8; e < deg; e += 8) {
      int i = col[st + e];
      ushort4 v = *(const ushort4*)((const char*)src + (((unsigned)i << 6) + coff));
      s0 += u2f(v.x); s1 += u2f(v.y); s2 += u2f(v.z); s3 += u2f(v.w);
    }
    s0 += __shfl_xor(s0, 8);  s1 += __shfl_xor(s1, 8);  s2 += __shfl_xor(s2, 8);  s3 += __shfl_xor(s3, 8);
    s0 += __shfl_xor(s0, 16); s1 += __shfl_xor(s1, 16); s2 += __shfl_xor(s2, 16); s3 += __shfl_xor(s3, 16);
    s0 += __shfl_xor(s0, 32); s1 += __shfl_xor(s1, 32); s2 += __shfl_xor(s2, 32); s3 += __shfl_xor(s3, 32);
    if (e8 == 0) {
      float inv = 1.f / (float)(deg > 1 ? deg : 1);
      ushort4 o; o.x = f2u(s0 * inv); o.y = f2u(s1 * inv); o.z = f2u(s2 * inv); o.w = f2u(s3 * inv);
      *(ushort4*)((char*)dst + (((unsigned)n << 6) + coff)) = o;
    }
  } else {
    int n = (b - 37500) * 4 + wave;
    int st = st_bb[n];
    int deg = ct_bb[n];
    float q0 = 0.f, q1 = 0.f, q2 = 0.f, q3 = 0.f;
    float r0 = 0.f, r1 = 0.f, r2 = 0.f, r3 = 0.f;
    #pragma unroll 2
    for (int e = e8; e < deg; e += 8) {
      int i = col_bb[st + e];
      unsigned boff = ((unsigned)i << 6) + coff;
      ushort4 vq = *(const ushort4*)((const char*)Q + boff);
      ushort4 vr = *(const ushort4*)((const char*)R + boff);
      q0 += u2f(vq.x); q1 += u2f(vq.y); q2 += u2f(vq.z); q3 += u2f(vq.w);
      r0 += u2f(vr.x); r1 += u2f(vr.y); r2 += u2f(vr.z); r3 += u2f(vr.w);
    }
    q0 += __shfl_xor(q0, 8);  q1 += __shfl_xor(q1, 8);  q2 += __shfl_xor(q2, 8);  q3 += __shfl_xor(q3, 8);
    r0 += __shfl_xor(r0, 8);  r1 += __shfl_xor(r1, 8);  r2 += __shfl_xor(r2, 8);  r3 += __shfl_xor(r3, 8);
    q0 += __shfl_xor(q0, 16); q1 += __shfl_xor(q1, 16); q2 += __shfl_xor(q2, 16); q3 += __shfl_xor(q3, 16);
    r0 += __shfl_xor(r0, 16); r1 += __shfl_xor(r1, 16); r2 += __shfl_xor(r2, 16); r3 += __shfl_xor(r3, 16);
    q0 += __shfl_xor(q0, 32); q1 += __shfl_xor(q1, 32); q2 += __shfl_xor(q2, 32); q3 += __shfl_xor(q3, 32);
    r0 += __shfl_xor(r0, 32); r1 += __shfl_xor(r1, 32); r2 += __shfl_xor(r2, 32); r3 += __shfl_xor(r3, 32);
    if (e8 == 0) {
      float inv = 1.f / (float)(deg > 1 ? deg : 1);
      ushort4 o1v; o1v.x = f2u(q0 * inv); o1v.y = f2u(q1 * inv); o1v.z = f2u(q2 * inv); o1v.w = f2u(q3 * inv);
      *(ushort4*)((char*)S + (((unsigned)n << 6) + coff)) = o1v;
      ushort4 o2v; o2v.x = f2u(r0 * inv); o2v.y = f2u(r1 * inv); o2v.z = f2u(r2 * inv); o2v.w = f2u(r3 * inv);
      *(ushort4*)((char*)T + (((unsigned)n << 6) + coff)) = o2v;
    }
  }
}

// ---- fused final, nt-split: block = (row-block, nt quadrant); 2 strips/wave ----
__global__ __launch_bounds__(256) void k_fin(
    const bf16* __restrict__ xa, const bf16* __restrict__ P, const bf16* __restrict__ P2,
    const bf16* __restrict__ xb, const bf16* __restrict__ Q, const bf16* __restrict__ R,
    const bf16* __restrict__ Q2, const bf16* __restrict__ S, const bf16* __restrict__ T,
    const bf16* __restrict__ Wfrag, const float* __restrict__ Bv,
    const int* __restrict__ cnt_aa, const int* __restrict__ cnt_ab, const int* __restrict__ cnt_bb,
    const float* __restrict__ c_a, const float* __restrict__ c_b,
    float* __restrict__ out) {
  int nt = blockIdx.x & 3;
  int blk = blockIdx.x >> 2;
  int wave = threadIdx.x >> 6, lane = threadIdx.x & 63;
  int l15 = lane & 15, l4 = lane >> 4;
  const size_t TOTA = (size_t)NA * 64, TOTB = (size_t)NB * 64;
  #define FRAG(mat, nt_) (*(const bf16x8*)(Wfrag + ((size_t)((mat) * 4 + (nt_)) * 64 + lane) * 8))
  const bf16x8 z8 = {0, 0, 0, 0, 0, 0, 0, 0};
  int col = nt * 16 + l15;

  if (blk < GF2A) {
    int row0 = (blk * 4 + wave) * 32;
    bf16x8 a[3][2];
    float m[2][4];
    #pragma unroll
    for (int s = 0; s < 2; ++s) {
      int r = row0 + s * 16 + l15;
      bool ok = r < NA;
      a[0][s] = ok ? *(const bf16x8*)(P2 + (size_t)r * 32 + l4 * 8) : z8;
      a[1][s] = ok ? *(const bf16x8*)(P  + (size_t)r * 32 + l4 * 8) : z8;
      a[2][s] = ok ? *(const bf16x8*)(xa + (size_t)r * 32 + l4 * 8) : z8;
      #pragma unroll
      for (int q = 0; q < 4; ++q) {
        int rr = row0 + s * 16 + l4 * 4 + q;
        m[s][q] = (rr < NA && cnt_aa[rr] > 0) ? 1.f : 0.f;
      }
    }
    float* h = out;
    float* cn = out + TOTA + TOTB;
    bf16x8 fr[12];
    #pragma unroll
    for (int gq = 0; gq < 12; ++gq) fr[gq] = FRAG(gq, nt);
    float bm[4], bc[4];
    #pragma unroll
    for (int g = 0; g < 4; ++g) { bm[g] = Bv[(g * 5 + 0) * 64 + col]; bc[g] = Bv[(g * 5 + 1) * 64 + col]; }
    #pragma unroll
    for (int s = 0; s < 2; ++s) {
      float cpre[4];
      #pragma unroll
      for (int q = 0; q < 4; ++q) {
        int rr = row0 + s * 16 + l4 * 4 + q;
        cpre[q] = (rr < NA) ? c_a[(size_t)rr * 64 + col] : 0.f;
      }
      f32x4 z[4];
      #pragma unroll
      for (int g = 0; g < 4; ++g) {
        f32x4 acc = {0.f, 0.f, 0.f, 0.f};
        acc = __builtin_amdgcn_mfma_f32_16x16x32_bf16(a[0][s], fr[g * 3 + 0], acc, 0, 0, 0);
        acc = __builtin_amdgcn_mfma_f32_16x16x32_bf16(a[1][s], fr[g * 3 + 1], acc, 0, 0, 0);
        acc = __builtin_amdgcn_mfma_f32_16x16x32_bf16(a[2][s], fr[g * 3 + 2], acc, 0, 0, 0);
        z[g] = acc;
      }
      #pragma unroll
      for (int q = 0; q < 4; ++q) {
        int rr = row0 + s * 16 + l4 * 4 + q;
        if (rr >= NA) continue;
        float zi = z[0][q] + m[s][q] * bm[0] + bc[0];
        float zf = z[1][q] + m[s][q] * bm[1] + bc[1];
        float zo = z[2][q] + m[s][q] * bm[2] + bc[2];
        float zg = z[3][q] + m[s][q] * bm[3] + bc[3];
        float ig = fast_sigmoid(zi);
        float fg = fast_sigmoid(zf);
        float og = fast_sigmoid(zo);
        float gg = fast_tanh(zg);
        size_t idx = (size_t)rr * 64 + col;
        float cv = fg * cpre[q] + ig * gg;
        h[idx] = og * fast_tanh(cv);
        cn[idx] = cv;
      }
    }
  } else {
    int bb = blk - GF2A;
    int row0 = (bb * 4 + wave) * 32;
    bf16x8 a[6][2];
    float mab[2][4], mbb[2][4];
    #pragma unroll
    for (int s = 0; s < 2; ++s) {
      int r = row0 + s * 16 + l15;
      bool ok = r < NB;
      a[0][s] = ok ? *(const bf16x8*)(Q2 + (size_t)r * 32 + l4 * 8) : z8;
      a[1][s] = ok ? *(const bf16x8*)(Q  + (size_t)r * 32 + l4 * 8) : z8;
      a[2][s] = ok ? *(const bf16x8*)(S  + (size_t)r * 32 + l4 * 8) : z8;
      a[3][s] = ok ? *(const bf16x8*)(T  + (size_t)r * 32 + l4 * 8) : z8;
      a[4][s] = ok ? *(const bf16x8*)(R  + (size_t)r * 32 + l4 * 8) : z8;
      a[5][s] = ok ? *(const bf16x8*)(xb + (size_t)r * 32 + l4 * 8) : z8;
      #pragma unroll
      for (int q = 0; q < 4; ++q) {
        int rr = row0 + s * 16 + l4 * 4 + q;
        bool okr = rr < NB;
        mab[s][q] = (okr && cnt_ab[rr] > 0) ? 1.f : 0.f;
        mbb[s][q] = (okr && cnt_bb[rr] > 0) ? 1.f : 0.f;
      }
    }
    float* h = out + TOTA;
    float* cn = out + 2 * TOTA + TOTB;
    float bm1[4], bm2[4], bc[4];
    #pragma unroll
    for (int g = 0; g < 4; ++g) {
      bm1[g] = Bv[(g * 5 + 2) * 64 + col];
      bm2[g] = Bv[(g * 5 + 3) * 64 + col];
      bc[g]  = Bv[(g * 5 + 4) * 64 + col];
    }
    float cpre[2][4];
    #pragma unroll
    for (int s = 0; s < 2; ++s)
      #pragma unroll
      for (int q = 0; q < 4; ++q) {
        int rr = row0 + s * 16 + l4 * 4 + q;
        cpre[s][q] = (rr < NB) ? c_b[(size_t)rr * 64 + col] : 0.f;
      }
    f32x4 z[2][4];
    #pragma unroll
    for (int s = 0; s < 2; ++s)
      #pragma unroll
      for (int g = 0; g < 4; ++g) z[s][g] = (f32x4){0.f, 0.f, 0.f, 0.f};
    #pragma unroll
    for (int g = 0; g < 4; ++g) {
      bf16x8 fr[6];
      #pragma unroll
      for (int t = 0; t < 6; ++t) fr[t] = FRAG(12 + g * 6 + t, nt);
      #pragma unroll
      for (int s = 0; s < 2; ++s) {
        #pragma unroll
        for (int t = 0; t < 6; ++t)
          z[s][g] = __builtin_amdgcn_mfma_f32_16x16x32_bf16(a[t][s], fr[t], z[s][g], 0, 0, 0);
      }
    }
    #pragma unroll
    for (int s = 0; s < 2; ++s) {
      #pragma unroll
      for (int q = 0; q < 4; ++q) {
        int rr = row0 + s * 16 + l4 * 4 + q;
        if (rr >= NB) continue;
        float zi = z[s][0][q] + mab[s][q] * bm1[0] + mbb[s][q] * bm2[0] + bc[0];
        float zf = z[s][1][q] + mab[s][q] * bm1[1] + mbb[s][q] * bm2[1] + bc[1];
        float zo = z[s][2][q] + mab[s][q] * bm1[2] + mbb[s][q] * bm2[2] + bc[2];
        float zg = z[s][3][q] + mab[s][q] * bm1[3] + mbb[s][q] * bm2[3] + bc[3];
        float ig = fast_sigmoid(zi);
        float fg = fast_sigmoid(zf);
        float og = fast_sigmoid(zo);
        float gg = fast_tanh(zg);
        size_t idx = (size_t)rr * 64 + col;
        float cv = fg * cpre[s][q] + ig * gg;
        h[idx] = og * fast_tanh(cv);
        cn[idx] = cv;
      }
    }
  }
  #undef FRAG
}

extern "C" void kernel_launch(void* const* d_in, const int* in_sizes, int n_in,
                              void* d_out, int out_size, void* d_ws, size_t ws_size,
                              hipStream_t stream) {
  (void)in_sizes; (void)n_in; (void)out_size; (void)ws_size;
  const float* x_a    = (const float*)d_in[0];
  const float* x_b    = (const float*)d_in[1];
  const float* c_a    = (const float*)d_in[2];
  const float* c_b    = (const float*)d_in[3];
  const float* lin_w  = (const float*)d_in[4];
  const float* lin_b  = (const float*)d_in[5];
  const float* conv_wl = (const float*)d_in[6];
  const float* conv_wr = (const float*)d_in[7];
  const float* conv_cb = (const float*)d_in[8];
  const int* src_aa = (const int*)d_in[9];
  const int* dst_aa = (const int*)d_in[10];
  const int* src_ab = (const int*)d_in[11];
  const int* dst_ab = (const int*)d_in[12];
  const int* src_bb = (const int*)d_in[13];
  const int* dst_bb = (const int*)d_in[14];

  char* ws = (char*)d_ws;
  size_t off = 0;
  auto alloc = [&](size_t bytes) -> char* {
    off = (off + 255) & ~(size_t)255;
    char* p = ws + off;
    off += bytes;
    return p;
  };
  bf16* xab = (bf16*)alloc((size_t)NA * 32 * 2);
  bf16* xbb = (bf16*)alloc((size_t)NB * 32 * 2);
  bf16* P   = (bf16*)alloc((size_t)NA * 32 * 2);
  bf16* P2  = (bf16*)alloc((size_t)NA * 32 * 2);
  bf16* Q   = (bf16*)alloc((size_t)NB * 32 * 2);
  bf16* R   = (bf16*)alloc((size_t)NB * 32 * 2);
  bf16* Q2  = (bf16*)alloc((size_t)NB * 32 * 2);
  bf16* S   = (bf16*)alloc((size_t)NB * 32 * 2);
  bf16* T   = (bf16*)alloc((size_t)NB * 32 * 2);
  float* Mbuf = (float*)alloc((size_t)20 * 2048 * 4);
  bf16* Wfrag = (bf16*)alloc((size_t)36 * 4 * 64 * 8 * 2);
  float* Bv = (float*)alloc((size_t)4 * 5 * 64 * 4);
  int* col_aa  = (int*)alloc((size_t)EAA * 4);
  int* col_ab  = (int*)alloc((size_t)EAB * 4);
  int* col_bb  = (int*)alloc((size_t)EBB * 4);
  int* pk_aa   = (int*)alloc((size_t)EAA * 4);
  int* pk_ab   = (int*)alloc((size_t)EAB * 4);
  int* pk_bb   = (int*)alloc((size_t)EBB * 4);
  int* start_aa = (int*)alloc((size_t)NA * 4);
  int* start_ab = (int*)alloc((size_t)NB * 4);
  int* start_bb = (int*)alloc((size_t)NB * 4);
  int* cnt_aa  = (int*)alloc((size_t)NA * 4);
  int* cnt_ab  = (int*)alloc((size_t)NB * 4);
  int* cnt_bb  = (int*)alloc((size_t)NB * 4);
  int* binAA   = (int*)alloc((size_t)BKA * NBKAA * 4);
  int* binAB   = (int*)alloc((size_t)BKB * NBKB * 4);
  int* binBB   = (int*)alloc((size_t)BKB * NBKB * 4);
  int* totAA   = (int*)alloc((size_t)NBKAA * 4);
  int* totAB   = (int*)alloc((size_t)NBKB * 4);
  int* totBB   = (int*)alloc((size_t)NBKB * 4);
  int* bsAA    = (int*)alloc((size_t)(NBKAA + 1) * 4);
  int* bsAB    = (int*)alloc((size_t)(NBKB + 1) * 4);
  int* bsBB    = (int*)alloc((size_t)(NBKB + 1) * 4);

  // weight folding (parallelized) + x cast
  kW1<<<20, 256, 0, stream>>>(lin_w, conv_wl, conv_wr, Mbuf);
  kW2<<<40, 256, 0, stream>>>(Mbuf, conv_wl, conv_wr, conv_cb, lin_b, Wfrag, Bv);
  k_cast2<<<4688, 256, 0, stream>>>(x_a, x_b, xab, xbb);

  // atomic-free CSR build (counting sort)
  kA_bin<<<BKA + 2 * BKB, 256, 0, stream>>>(dst_aa, dst_ab, dst_bb, binAA, binAB, binBB);
  kB1<<<(NBKAA + 2 * NBKB) / 4, 256, 0, stream>>>(binAA, binAB, binBB, totAA, totAB, totBB);
  kB2<<<3, 256, 0, stream>>>(totAA, totAB, totBB, bsAA, bsAB, bsBB);
  kC_scatter<<<BKA + 2 * BKB, 256, 0, stream>>>(src_aa, dst_aa, src_ab, dst_ab, src_bb, dst_bb,
                                                binAA, binAB, binBB, bsAA, bsAB, bsBB,
                                                pk_aa, pk_ab, pk_bb);
  kD_nodesort<<<NBKAA + 2 * NBKB, 256, 0, stream>>>(pk_aa, pk_ab, pk_bb, bsAA, bsAB, bsBB,
                                                    col_aa, col_ab, col_bb,
                                                    start_aa, cnt_aa, start_ab, cnt_ab,
                                                    start_bb, cnt_bb);

  // aggregation chains (32-ch rows only)
  k_aggP1<<<50000, 256, 0, stream>>>(xab, xbb, P, Q, R,
                                     start_aa, cnt_aa, col_aa,
                                     start_ab, cnt_ab, col_ab,
                                     start_bb, cnt_bb, col_bb);
  k_aggP2<<<50000, 256, 0, stream>>>(P, Q, R, P2, Q2, S, T,
                                     start_aa, cnt_aa, col_aa,
                                     start_ab, cnt_ab, col_ab,
                                     start_bb, cnt_bb, col_bb);

  // fused z-matmul + LSTM, nt-split grid (4x blocks)
  k_fin<<<(GF2A + GF2B) * 4, 256, 0, stream>>>(xab, P, P2, xbb, Q, R, Q2, S, T,
                                               Wfrag, Bv, cnt_aa, cnt_ab, cnt_bb,
                                               c_a, c_b, (float*)d_out);
}

// Round 14
// 287.145 us; speedup vs baseline: 1.0254x; 1.0254x over previous
//
#include <hip/hip_runtime.h>
#include <hip/hip_bf16.h>

#define NA 100000
#define NB 50000
#define EAA 1600000
#define EAB 800000
#define EBB 800000

#define NBKAA 782   // ceil(NA/128)
#define NBKB  391   // ceil(NB/128)
#define BKA 200     // blocks for aa set (8000 edges each)
#define BKB 100     // blocks for ab/bb sets (8000 edges each)
#define DCAP 4096   // kD staging capacity

#define GF3A 3125   // ceil(NA/32) fin blocks, A (32 rows, wave = nt quadrant)
#define GF3B 1563   // ceil(NB/32) fin blocks, B

typedef __hip_bfloat16 bf16;
typedef __attribute__((ext_vector_type(8))) short bf16x8;
typedef __attribute__((ext_vector_type(4))) float f32x4;

__device__ __forceinline__ float u2f(unsigned short u) {
  union { unsigned int i; float f; } x; x.i = ((unsigned int)u) << 16; return x.f;
}
__device__ __forceinline__ unsigned short f2u(float f) {
  __hip_bfloat16 h = __float2bfloat16(f);
  return *reinterpret_cast<unsigned short*>(&h);
}
__device__ __forceinline__ short f2bs(float f) {
  __hip_bfloat16 h = __float2bfloat16(f);
  return *reinterpret_cast<short*>(&h);
}
__device__ __forceinline__ float fast_sigmoid(float z) {
  return 1.f / (1.f + __expf(-z));
}
__device__ __forceinline__ float fast_tanh(float z) {
  z = fminf(fmaxf(z, -15.f), 15.f);
  float t = __expf(2.f * z);
  return (t - 1.f) / (t + 1.f);
}

// =============== CSR build: atomic-free counting sort ===============
__global__ __launch_bounds__(256) void kA_bin(
    const int* __restrict__ d1, const int* __restrict__ d2, const int* __restrict__ d3,
    int* __restrict__ binAA, int* __restrict__ binAB, int* __restrict__ binBB) {
  __shared__ int h[1024];
  int blk = blockIdx.x;
  const int* dst; int* out; int e0, nbk;
  if (blk < BKA)            { dst = d1; out = binAA + blk * NBKAA; e0 = blk * 8000; nbk = NBKAA; }
  else if (blk < BKA + BKB) { int k = blk - BKA; dst = d2; out = binAB + k * NBKB; e0 = k * 8000; nbk = NBKB; }
  else                      { int k = blk - BKA - BKB; dst = d3; out = binBB + k * NBKB; e0 = k * 8000; nbk = NBKB; }
  for (int i = threadIdx.x; i < nbk; i += 256) h[i] = 0;
  __syncthreads();
  for (int i = threadIdx.x; i < 8000; i += 256) atomicAdd(&h[dst[e0 + i] >> 7], 1);
  __syncthreads();
  for (int i = threadIdx.x; i < nbk; i += 256) out[i] = h[i];
}

__global__ __launch_bounds__(256) void kB1(
    int* __restrict__ binAA, int* __restrict__ binAB, int* __restrict__ binBB,
    int* __restrict__ totAA, int* __restrict__ totAB, int* __restrict__ totBB) {
  int wave = threadIdx.x >> 6, lane = threadIdx.x & 63;
  int wid = blockIdx.x * 4 + wave;
  int* bin; int* tot; int b, nblk, nbk;
  if (wid < NBKAA)              { bin = binAA; tot = totAA; b = wid; nblk = BKA; nbk = NBKAA; }
  else if (wid < NBKAA + NBKB)  { bin = binAB; tot = totAB; b = wid - NBKAA; nblk = BKB; nbk = NBKB; }
  else                          { bin = binBB; tot = totBB; b = wid - NBKAA - NBKB; nblk = BKB; nbk = NBKB; }
  int C = (nblk + 63) / 64;  // 4 for aa, 2 for ab/bb
  int vals[4]; int s = 0;
  for (int j = 0; j < C; ++j) { int k = lane * C + j; vals[j] = (k < nblk) ? bin[k * nbk + b] : 0; s += vals[j]; }
  int pre = s;
  for (int o = 1; o < 64; o <<= 1) { int x = __shfl_up(pre, o); if (lane >= o) pre += x; }
  int run = pre - s;
  for (int j = 0; j < C; ++j) { int k = lane * C + j; if (k < nblk) { int v = vals[j]; bin[k * nbk + b] = run; run += v; } }
  if (lane == 63) tot[b] = pre;
}

__global__ __launch_bounds__(256) void kB2(
    const int* __restrict__ totAA, const int* __restrict__ totAB, const int* __restrict__ totBB,
    int* __restrict__ bsAA, int* __restrict__ bsAB, int* __restrict__ bsBB) {
  __shared__ int part[256];
  int set = blockIdx.x; const int* tot; int* bs; int nbk;
  if (set == 0)      { tot = totAA; bs = bsAA; nbk = NBKAA; }
  else if (set == 1) { tot = totAB; bs = bsAB; nbk = NBKB; }
  else               { tot = totBB; bs = bsBB; nbk = NBKB; }
  int t = threadIdx.x;
  int v[4]; int s = 0;
  #pragma unroll
  for (int j = 0; j < 4; ++j) { int k = t * 4 + j; v[j] = (k < nbk) ? tot[k] : 0; s += v[j]; }
  part[t] = s;
  __syncthreads();
  for (int o = 1; o < 256; o <<= 1) {
    int x = (t >= o) ? part[t - o] : 0;
    __syncthreads();
    part[t] += x;
    __syncthreads();
  }
  int run = part[t] - s;
  #pragma unroll
  for (int j = 0; j < 4; ++j) { int k = t * 4 + j; if (k < nbk) { bs[k] = run; run += v[j]; } }
  if (t == 255) bs[nbk] = part[255];
}

__global__ __launch_bounds__(256) void kC_scatter(
    const int* __restrict__ s1, const int* __restrict__ d1,
    const int* __restrict__ s2, const int* __restrict__ d2,
    const int* __restrict__ s3, const int* __restrict__ d3,
    const int* __restrict__ binAA, const int* __restrict__ binAB, const int* __restrict__ binBB,
    const int* __restrict__ bsAA, const int* __restrict__ bsAB, const int* __restrict__ bsBB,
    int* __restrict__ pkAA, int* __restrict__ pkAB, int* __restrict__ pkBB) {
  __shared__ int baseL[1024];
  __shared__ int run[1024];
  int blk = blockIdx.x;
  const int* src; const int* dst; const int* bin; const int* bs; int* pk; int e0, nbk, bofs;
  if (blk < BKA)            { src = s1; dst = d1; bin = binAA; bs = bsAA; pk = pkAA; e0 = blk * 8000; nbk = NBKAA; bofs = blk * NBKAA; }
  else if (blk < BKA + BKB) { int k = blk - BKA; src = s2; dst = d2; bin = binAB; bs = bsAB; pk = pkAB; e0 = k * 8000; nbk = NBKB; bofs = k * NBKB; }
  else                      { int k = blk - BKA - BKB; src = s3; dst = d3; bin = binBB; bs = bsBB; pk = pkBB; e0 = k * 8000; nbk = NBKB; bofs = k * NBKB; }
  for (int i = threadIdx.x; i < nbk; i += 256) { baseL[i] = bs[i] + bin[bofs + i]; run[i] = 0; }
  __syncthreads();
  for (int i = threadIdx.x; i < 8000; i += 256) {
    int d = dst[e0 + i];
    int b = d >> 7;
    int off = atomicAdd(&run[b], 1);
    pk[baseL[b] + off] = src[e0 + i] | ((d & 127) << 24);
  }
}

__global__ __launch_bounds__(256) void kD_nodesort(
    const int* __restrict__ pkAA, const int* __restrict__ pkAB, const int* __restrict__ pkBB,
    const int* __restrict__ bsAA, const int* __restrict__ bsAB, const int* __restrict__ bsBB,
    int* __restrict__ colAA, int* __restrict__ colAB, int* __restrict__ colBB,
    int* __restrict__ stAA, int* __restrict__ ctAA,
    int* __restrict__ stAB, int* __restrict__ ctAB,
    int* __restrict__ stBB, int* __restrict__ ctBB) {
  __shared__ int hist[128], nodeOff[129], run[128];
  __shared__ int stage[DCAP];
  int wid = blockIdx.x;
  const int* pk; const int* bs; int* col; int* stn; int* ctn; int b, N;
  if (wid < NBKAA)             { pk = pkAA; bs = bsAA; col = colAA; stn = stAA; ctn = ctAA; b = wid; N = NA; }
  else if (wid < NBKAA + NBKB) { pk = pkAB; bs = bsAB; col = colAB; stn = stAB; ctn = ctAB; b = wid - NBKAA; N = NB; }
  else                         { pk = pkBB; bs = bsBB; col = colBB; stn = stBB; ctn = ctBB; b = wid - NBKAA - NBKB; N = NB; }
  int node0 = b * 128;
  int base = bs[b], cntB = bs[b + 1] - base;
  int t = threadIdx.x;
  if (t < 128) hist[t] = 0;
  __syncthreads();
  for (int i = t; i < cntB; i += 256) atomicAdd(&hist[pk[base + i] >> 24], 1);
  __syncthreads();
  if (t < 64) {
    int v0 = hist[2 * t], v1 = hist[2 * t + 1];
    int s = v0 + v1; int pre = s;
    for (int o = 1; o < 64; o <<= 1) { int x = __shfl_up(pre, o); if (t >= o) pre += x; }
    int ex = pre - s;
    nodeOff[2 * t] = ex; nodeOff[2 * t + 1] = ex + v0;
    if (t == 63) nodeOff[128] = pre;
    run[2 * t] = 0; run[2 * t + 1] = 0;
  }
  __syncthreads();
  if (t < 128) {
    int n = node0 + t;
    if (n < N) { ctn[n] = hist[t]; stn[n] = base + nodeOff[t]; }
  }
  if (cntB <= DCAP) {
    for (int i = t; i < cntB; i += 256) {
      int e = pk[base + i]; int ln = e >> 24;
      int off = atomicAdd(&run[ln], 1);
      stage[nodeOff[ln] + off] = e & 0xFFFFFF;
    }
    __syncthreads();
    for (int i = t; i < cntB; i += 256) col[base + i] = stage[i];
  } else {
    for (int i = t; i < cntB; i += 256) {
      int e = pk[base + i]; int ln = e >> 24;
      int off = atomicAdd(&run[ln], 1);
      col[base + nodeOff[ln] + off] = e & 0xFFFFFF;
    }
  }
}

// ---------------- cast x (f32) -> bf16 ----------------
__global__ __launch_bounds__(256) void k_cast2(const float* __restrict__ xa, const float* __restrict__ xb,
                                               bf16* __restrict__ ya, bf16* __restrict__ yb) {
  int i = blockIdx.x * 256 + threadIdx.x;
  const float* x; bf16* y; int base;
  if (i < 800000)       { x = xa; y = ya; base = i * 4; }
  else if (i < 1200000) { x = xb; y = yb; base = (i - 800000) * 4; }
  else return;
  float4 v = *(const float4*)(x + base);
  ushort4 o; o.x = f2u(v.x); o.y = f2u(v.y); o.z = f2u(v.z); o.w = f2u(v.w);
  *(ushort4*)(y + base) = o;
}

// ---- kW1: phase-1 intermediates M[term][g] = L @ R  (20 blocks) ----
__global__ __launch_bounds__(256) void kW1(
    const float* __restrict__ lin_w, const float* __restrict__ wl, const float* __restrict__ wr,
    float* __restrict__ Mbuf) {
  __shared__ float Ls[32][64];
  __shared__ float Rs[64][64];
  int id = blockIdx.x, term = id >> 2, g = id & 3;
  const float* L = lin_w + ((size_t)g * 2 + (term >= 3 ? 1 : 0)) * 2048;
  const float* R1; const float* R2 = nullptr;
  switch (term) {
    case 0: R1 = wl + ((size_t)(g * 2) * 3 + 0) * 4096; break;
    case 1: R1 = wr + ((size_t)(g * 2) * 3 + 0) * 4096; break;
    case 2: R1 = wl + ((size_t)(g * 2) * 3 + 1) * 4096; break;
    case 3: R1 = wl + ((size_t)(g * 2) * 3 + 2) * 4096; break;
    default: R1 = wr + ((size_t)(g * 2) * 3 + 1) * 4096; R2 = wr + ((size_t)(g * 2) * 3 + 2) * 4096; break;
  }
  for (int i = threadIdx.x; i < 2048; i += 256) Ls[i >> 6][i & 63] = L[i];
  for (int i = threadIdx.x; i < 4096; i += 256) Rs[i >> 6][i & 63] = R2 ? (R1[i] + R2[i]) : R1[i];
  __syncthreads();
  int c = threadIdx.x & 63, rq = threadIdx.x >> 6;
  float acc[8] = {0, 0, 0, 0, 0, 0, 0, 0};
  for (int k = 0; k < 64; ++k) {
    float rv = Rs[k][c];
    #pragma unroll
    for (int i = 0; i < 8; ++i) acc[i] += Ls[rq * 8 + i][k] * rv;
  }
  #pragma unroll
  for (int i = 0; i < 8; ++i)
    Mbuf[(size_t)(term * 4 + g) * 2048 + (rq * 8 + i) * 64 + c] = acc[i];
}

// ---- kW2: 36 output mats (bf16 MFMA B-fragments) + 4 bias blocks ----
__global__ __launch_bounds__(256) void kW2(
    const float* __restrict__ Mbuf, const float* __restrict__ wl, const float* __restrict__ wr,
    const float* __restrict__ cbv, const float* __restrict__ lin_b,
    bf16* __restrict__ Wfrag, float* __restrict__ Bv) {
  __shared__ float Ps[2][32][65];
  __shared__ float Ws[2][64][64];
  int blk = blockIdx.x;
  if (blk >= 36) {
    int g = blk - 36;
    if (threadIdx.x < 64) {
      int c = threadIdx.x;
      const float* b00 = cbv + (size_t)((g * 2 + 0) * 3 + 0) * 64;
      const float* b10 = cbv + (size_t)((g * 2 + 0) * 3 + 1) * 64;
      const float* b20 = cbv + (size_t)((g * 2 + 0) * 3 + 2) * 64;
      const float* b01 = cbv + (size_t)((g * 2 + 1) * 3 + 0) * 64;
      const float* b11 = cbv + (size_t)((g * 2 + 1) * 3 + 1) * 64;
      const float* b21 = cbv + (size_t)((g * 2 + 1) * 3 + 2) * 64;
      const float* wl01 = wl + (size_t)((g * 2 + 1) * 3 + 0) * 4096;
      const float* wl11 = wl + (size_t)((g * 2 + 1) * 3 + 1) * 4096;
      const float* wl21 = wl + (size_t)((g * 2 + 1) * 3 + 2) * 4096;
      const float* wr01 = wr + (size_t)((g * 2 + 1) * 3 + 0) * 4096;
      const float* wr11 = wr + (size_t)((g * 2 + 1) * 3 + 1) * 4096;
      const float* wr21 = wr + (size_t)((g * 2 + 1) * 3 + 2) * 4096;
      float s_maa = 0.f, s_ca = 0.f, s_mab = 0.f, s_mbb = 0.f, s_cb = 0.f;
      for (int k = 0; k < 64; ++k) {
        float v0 = b00[k], vb = b10[k] + b20[k];
        s_maa += v0 * wl01[k * 64 + c];
        s_ca  += v0 * wr01[k * 64 + c];
        s_mab += v0 * wl11[k * 64 + c];
        s_mbb += vb * wl21[k * 64 + c];
        s_cb  += vb * (wr11[k * 64 + c] + wr21[k * 64 + c]);
      }
      Bv[(g * 5 + 0) * 64 + c] = s_maa;
      Bv[(g * 5 + 1) * 64 + c] = s_ca + b01[c] + lin_b[(g * 2 + 0) * 64 + c];
      Bv[(g * 5 + 2) * 64 + c] = s_mab;
      Bv[(g * 5 + 3) * 64 + c] = s_mbb;
      Bv[(g * 5 + 4) * 64 + c] = s_cb + b11[c] + b21[c] + lin_b[(g * 2 + 1) * 64 + c];
    }
    return;
  }
  int mat = blk, g, m;
  if (blk < 12) { g = blk / 3; m = blk % 3; }
  else          { g = (blk - 12) / 6; m = (blk - 12) % 6 + 3; }
  const float* wl01 = wl + (size_t)((g * 2 + 1) * 3 + 0) * 4096;
  const float* wl11 = wl + (size_t)((g * 2 + 1) * 3 + 1) * 4096;
  const float* wl21 = wl + (size_t)((g * 2 + 1) * 3 + 2) * 4096;
  const float* wr01 = wr + (size_t)((g * 2 + 1) * 3 + 0) * 4096;
  const float* wr11 = wr + (size_t)((g * 2 + 1) * 3 + 1) * 4096;
  const float* wr21 = wr + (size_t)((g * 2 + 1) * 3 + 2) * 4096;
  int   p1t, p2t = -1;
  const float *w1a = nullptr, *w1b = nullptr, *w2a = nullptr, *w2b = nullptr;
  switch (m) {
    case 0: p1t = 0; w1a = wl01; break;
    case 1: p1t = 1; w1a = wl01; p2t = 0; w2a = wr01; break;
    case 2: p1t = 1; w1a = wr01; break;
    case 3: p1t = 0; w1a = wl11; break;
    case 4: p1t = 1; w1a = wl11; p2t = 2; w2a = wr11; w2b = wr21; break;
    case 5: p1t = 2; w1a = wl21; break;
    case 6: p1t = 3; w1a = wl21; break;
    case 7: p1t = 3; w1a = wr11; w1b = wr21; p2t = 4; w2a = wl21; break;
    default: p1t = 4; w1a = wr11; w1b = wr21; break;
  }
  int nprod = (p2t >= 0) ? 2 : 1;
  for (int i = threadIdx.x; i < 2048; i += 256) Ps[0][i >> 6][i & 63] = Mbuf[(size_t)(p1t * 4 + g) * 2048 + i];
  for (int i = threadIdx.x; i < 4096; i += 256) Ws[0][i >> 6][i & 63] = w1b ? (w1a[i] + w1b[i]) : w1a[i];
  if (nprod == 2) {
    for (int i = threadIdx.x; i < 2048; i += 256) Ps[1][i >> 6][i & 63] = Mbuf[(size_t)(p2t * 4 + g) * 2048 + i];
    for (int i = threadIdx.x; i < 4096; i += 256) Ws[1][i >> 6][i & 63] = w2b ? (w2a[i] + w2b[i]) : w2a[i];
  }
  __syncthreads();
  int nt = threadIdx.x >> 6, lane = threadIdx.x & 63;
  int c = nt * 16 + (lane & 15), kb = (lane >> 4) * 8;
  float acc[8] = {0, 0, 0, 0, 0, 0, 0, 0};
  for (int k = 0; k < 64; ++k) {
    float w1v = Ws[0][k][c];
    #pragma unroll
    for (int j = 0; j < 8; ++j) acc[j] += Ps[0][kb + j][k] * w1v;
  }
  if (nprod == 2) {
    for (int k = 0; k < 64; ++k) {
      float w2v = Ws[1][k][c];
      #pragma unroll
      for (int j = 0; j < 8; ++j) acc[j] += Ps[1][kb + j][k] * w2v;
    }
  }
  bf16x8 v;
  #pragma unroll
  for (int j = 0; j < 8; ++j) v[j] = f2bs(acc[j]);
  *(bf16x8*)(Wfrag + ((size_t)(mat * 4 + nt) * 64 + lane) * 8) = v;
}

// ---- pass-1 32-ch mean agg: P=A_aa(xa), Q=A_ab(xa), R=A_bb(xb); 8 edge-slots/wave ----
__global__ __launch_bounds__(256) void k_aggP1(
    const bf16* __restrict__ xa, const bf16* __restrict__ xb,
    bf16* __restrict__ P, bf16* __restrict__ Q, bf16* __restrict__ R,
    const int* __restrict__ st_aa, const int* __restrict__ ct_aa, const int* __restrict__ col_aa,
    const int* __restrict__ st_ab, const int* __restrict__ ct_ab, const int* __restrict__ col_ab,
    const int* __restrict__ st_bb, const int* __restrict__ ct_bb, const int* __restrict__ col_bb) {
  int b = blockIdx.x;
  const bf16* src; bf16* dst; const int* start; const int* cnt; const int* col; int n0;
  if (b < 25000)      { src = xa; dst = P; start = st_aa; cnt = ct_aa; col = col_aa; n0 = b * 4; }
  else if (b < 37500) { src = xa; dst = Q; start = st_ab; cnt = ct_ab; col = col_ab; n0 = (b - 25000) * 4; }
  else                { src = xb; dst = R; start = st_bb; cnt = ct_bb; col = col_bb; n0 = (b - 37500) * 4; }
  int wave = threadIdx.x >> 6, lane = threadIdx.x & 63;
  int n = n0 + wave;
  int e8 = lane >> 3, c8 = lane & 7;
  unsigned coff = (unsigned)(c8 << 3);
  int st = start[n];
  int deg = cnt[n];
  float s0 = 0.f, s1 = 0.f, s2 = 0.f, s3 = 0.f;
  #pragma unroll 2
  for (int e = e8; e < deg; e += 8) {
    int i = col[st + e];
    ushort4 v = *(const ushort4*)((const char*)src + (((unsigned)i << 6) + coff));
    s0 += u2f(v.x); s1 += u2f(v.y); s2 += u2f(v.z); s3 += u2f(v.w);
  }
  s0 += __shfl_xor(s0, 8);  s1 += __shfl_xor(s1, 8);  s2 += __shfl_xor(s2, 8);  s3 += __shfl_xor(s3, 8);
  s0 += __shfl_xor(s0, 16); s1 += __shfl_xor(s1, 16); s2 += __shfl_xor(s2, 16); s3 += __shfl_xor(s3, 16);
  s0 += __shfl_xor(s0, 32); s1 += __shfl_xor(s1, 32); s2 += __shfl_xor(s2, 32); s3 += __shfl_xor(s3, 32);
  if (e8 == 0) {
    float inv = 1.f / (float)(deg > 1 ? deg : 1);
    ushort4 o; o.x = f2u(s0 * inv); o.y = f2u(s1 * inv); o.z = f2u(s2 * inv); o.w = f2u(s3 * inv);
    *(ushort4*)((char*)dst + (((unsigned)n << 6) + coff)) = o;
  }
}

// ---- pass-2: P2=A_aa(P), Q2=A_ab(P), S=A_bb(Q) & T=A_bb(R) fused; 8 edge-slots/wave ----
__global__ __launch_bounds__(256) void k_aggP2(
    const bf16* __restrict__ P, const bf16* __restrict__ Q, const bf16* __restrict__ R,
    bf16* __restrict__ P2, bf16* __restrict__ Q2, bf16* __restrict__ S, bf16* __restrict__ T,
    const int* __restrict__ st_aa, const int* __restrict__ ct_aa, const int* __restrict__ col_aa,
    const int* __restrict__ st_ab, const int* __restrict__ ct_ab, const int* __restrict__ col_ab,
    const int* __restrict__ st_bb, const int* __restrict__ ct_bb, const int* __restrict__ col_bb) {
  int b = blockIdx.x;
  int wave = threadIdx.x >> 6, lane = threadIdx.x & 63;
  int e8 = lane >> 3, c8 = lane & 7;
  unsigned coff = (unsigned)(c8 << 3);
  if (b < 37500) {
    const bf16* src; bf16* dst; const int* start; const int* cnt; const int* col; int n0;
    if (b < 25000) { src = P; dst = P2; start = st_aa; cnt = ct_aa; col = col_aa; n0 = b * 4; }
    else           { src = P; dst = Q2; start = st_ab; cnt = ct_ab; col = col_ab; n0 = (b - 25000) * 4; }
    int n = n0 + wave;
    int st = start[n];
    int deg = cnt[n];
    float s0 = 0.f, s1 = 0.f, s2 = 0.f, s3 = 0.f;
    #pragma unroll 2
    for (int e = e8; e < deg; e += 8) {
      int i = col[st + e];
      ushort4 v = *(const ushort4*)((const char*)src + (((unsigned)i << 6) + coff));
      s0 += u2f(v.x); s1 += u2f(v.y); s2 += u2f(v.z); s3 += u2f(v.w);
    }
    s0 += __shfl_xor(s0, 8);  s1 += __shfl_xor(s1, 8);  s2 += __shfl_xor(s2, 8);  s3 += __shfl_xor(s3, 8);
    s0 += __shfl_xor(s0, 16); s1 += __shfl_xor(s1, 16); s2 += __shfl_xor(s2, 16); s3 += __shfl_xor(s3, 16);
    s0 += __shfl_xor(s0, 32); s1 += __shfl_xor(s1, 32); s2 += __shfl_xor(s2, 32); s3 += __shfl_xor(s3, 32);
    if (e8 == 0) {
      float inv = 1.f / (float)(deg > 1 ? deg : 1);
      ushort4 o; o.x = f2u(s0 * inv); o.y = f2u(s1 * inv); o.z = f2u(s2 * inv); o.w = f2u(s3 * inv);
      *(ushort4*)((char*)dst + (((unsigned)n << 6) + coff)) = o;
    }
  } else {
    int n = (b - 37500) * 4 + wave;
    int st = st_bb[n];
    int deg = ct_bb[n];
    float q0 = 0.f, q1 = 0.f, q2 = 0.f, q3 = 0.f;
    float r0 = 0.f, r1 = 0.f, r2 = 0.f, r3 = 0.f;
    #pragma unroll 2
    for (int e = e8; e < deg; e += 8) {
      int i = col_bb[st + e];
      unsigned boff = ((unsigned)i << 6) + coff;
      ushort4 vq = *(const ushort4*)((const char*)Q + boff);
      ushort4 vr = *(const ushort4*)((const char*)R + boff);
      q0 += u2f(vq.x); q1 += u2f(vq.y); q2 += u2f(vq.z); q3 += u2f(vq.w);
      r0 += u2f(vr.x); r1 += u2f(vr.y); r2 += u2f(vr.z); r3 += u2f(vr.w);
    }
    q0 += __shfl_xor(q0, 8);  q1 += __shfl_xor(q1, 8);  q2 += __shfl_xor(q2, 8);  q3 += __shfl_xor(q3, 8);
    r0 += __shfl_xor(r0, 8);  r1 += __shfl_xor(r1, 8);  r2 += __shfl_xor(r2, 8);  r3 += __shfl_xor(r3, 8);
    q0 += __shfl_xor(q0, 16); q1 += __shfl_xor(q1, 16); q2 += __shfl_xor(q2, 16); q3 += __shfl_xor(q3, 16);
    r0 += __shfl_xor(r0, 16); r1 += __shfl_xor(r1, 16); r2 += __shfl_xor(r2, 16); r3 += __shfl_xor(r3, 16);
    q0 += __shfl_xor(q0, 32); q1 += __shfl_xor(q1, 32); q2 += __shfl_xor(q2, 32); q3 += __shfl_xor(q3, 32);
    r0 += __shfl_xor(r0, 32); r1 += __shfl_xor(r1, 32); r2 += __shfl_xor(r2, 32); r3 += __shfl_xor(r3, 32);
    if (e8 == 0) {
      float inv = 1.f / (float)(deg > 1 ? deg : 1);
      ushort4 o1v; o1v.x = f2u(q0 * inv); o1v.y = f2u(q1 * inv); o1v.z = f2u(q2 * inv); o1v.w = f2u(q3 * inv);
      *(ushort4*)((char*)S + (((unsigned)n << 6) + coff)) = o1v;
      ushort4 o2v; o2v.x = f2u(r0 * inv); o2v.y = f2u(r1 * inv); o2v.z = f2u(r2 * inv); o2v.w = f2u(r3 * inv);
      *(ushort4*)((char*)T + (((unsigned)n << 6) + coff)) = o2v;
    }
  }
}

// ---- fused final: block = 32 rows, wave = nt quadrant (planes read once, full-row writes) ----
__global__ __launch_bounds__(256) void k_fin(
    const bf16* __restrict__ xa, const bf16* __restrict__ P, const bf16* __restrict__ P2,
    const bf16* __restrict__ xb, const bf16* __restrict__ Q, const bf16* __restrict__ R,
    const bf16* __restrict__ Q2, const bf16* __restrict__ S, const bf16* __restrict__ T,
    const bf16* __restrict__ Wfrag, const float* __restrict__ Bv,
    const int* __restrict__ cnt_aa, const int* __restrict__ cnt_ab, const int* __restrict__ cnt_bb,
    const float* __restrict__ c_a, const float* __restrict__ c_b,
    float* __restrict__ out) {
  int blk = blockIdx.x;
  int nt = threadIdx.x >> 6, lane = threadIdx.x & 63;   // wave index = nt quadrant
  int l15 = lane & 15, l4 = lane >> 4;
  const size_t TOTA = (size_t)NA * 64, TOTB = (size_t)NB * 64;
  #define FRAG(mat, nt_) (*(const bf16x8*)(Wfrag + ((size_t)((mat) * 4 + (nt_)) * 64 + lane) * 8))
  const bf16x8 z8 = {0, 0, 0, 0, 0, 0, 0, 0};
  int col = nt * 16 + l15;

  if (blk < GF3A) {
    int row0 = blk * 32;
    bf16x8 a[3][2];
    float m[2][4];
    #pragma unroll
    for (int s = 0; s < 2; ++s) {
      int r = row0 + s * 16 + l15;
      bool ok = r < NA;
      a[0][s] = ok ? *(const bf16x8*)(P2 + (size_t)r * 32 + l4 * 8) : z8;
      a[1][s] = ok ? *(const bf16x8*)(P  + (size_t)r * 32 + l4 * 8) : z8;
      a[2][s] = ok ? *(const bf16x8*)(xa + (size_t)r * 32 + l4 * 8) : z8;
      #pragma unroll
      for (int q = 0; q < 4; ++q) {
        int rr = row0 + s * 16 + l4 * 4 + q;
        m[s][q] = (rr < NA && cnt_aa[rr] > 0) ? 1.f : 0.f;
      }
    }
    float* h = out;
    float* cn = out + TOTA + TOTB;
    bf16x8 fr[12];
    #pragma unroll
    for (int gq = 0; gq < 12; ++gq) fr[gq] = FRAG(gq, nt);
    float bm[4], bc[4];
    #pragma unroll
    for (int g = 0; g < 4; ++g) { bm[g] = Bv[(g * 5 + 0) * 64 + col]; bc[g] = Bv[(g * 5 + 1) * 64 + col]; }
    #pragma unroll
    for (int s = 0; s < 2; ++s) {
      float cpre[4];
      #pragma unroll
      for (int q = 0; q < 4; ++q) {
        int rr = row0 + s * 16 + l4 * 4 + q;
        cpre[q] = (rr < NA) ? c_a[(size_t)rr * 64 + col] : 0.f;
      }
      f32x4 z[4];
      #pragma unroll
      for (int g = 0; g < 4; ++g) {
        f32x4 acc = {0.f, 0.f, 0.f, 0.f};
        acc = __builtin_amdgcn_mfma_f32_16x16x32_bf16(a[0][s], fr[g * 3 + 0], acc, 0, 0, 0);
        acc = __builtin_amdgcn_mfma_f32_16x16x32_bf16(a[1][s], fr[g * 3 + 1], acc, 0, 0, 0);
        acc = __builtin_amdgcn_mfma_f32_16x16x32_bf16(a[2][s], fr[g * 3 + 2], acc, 0, 0, 0);
        z[g] = acc;
      }
      #pragma unroll
      for (int q = 0; q < 4; ++q) {
        int rr = row0 + s * 16 + l4 * 4 + q;
        if (rr >= NA) continue;
        float zi = z[0][q] + m[s][q] * bm[0] + bc[0];
        float zf = z[1][q] + m[s][q] * bm[1] + bc[1];
        float zo = z[2][q] + m[s][q] * bm[2] + bc[2];
        float zg = z[3][q] + m[s][q] * bm[3] + bc[3];
        float ig = fast_sigmoid(zi);
        float fg = fast_sigmoid(zf);
        float og = fast_sigmoid(zo);
        float gg = fast_tanh(zg);
        size_t idx = (size_t)rr * 64 + col;
        float cv = fg * cpre[q] + ig * gg;
        h[idx] = og * fast_tanh(cv);
        cn[idx] = cv;
      }
    }
  } else {
    int bb = blk - GF3A;
    int row0 = bb * 32;
    bf16x8 a[6][2];
    float mab[2][4], mbb[2][4];
    #pragma unroll
    for (int s = 0; s < 2; ++s) {
      int r = row0 + s * 16 + l15;
      bool ok = r < NB;
      a[0][s] = ok ? *(const bf16x8*)(Q2 + (size_t)r * 32 + l4 * 8) : z8;
      a[1][s] = ok ? *(const bf16x8*)(Q  + (size_t)r * 32 + l4 * 8) : z8;
      a[2][s] = ok ? *(const bf16x8*)(S  + (size_t)r * 32 + l4 * 8) : z8;
      a[3][s] = ok ? *(const bf16x8*)(T  + (size_t)r * 32 + l4 * 8) : z8;
      a[4][s] = ok ? *(const bf16x8*)(R  + (size_t)r * 32 + l4 * 8) : z8;
      a[5][s] = ok ? *(const bf16x8*)(xb + (size_t)r * 32 + l4 * 8) : z8;
      #pragma unroll
      for (int q = 0; q < 4; ++q) {
        int rr = row0 + s * 16 + l4 * 4 + q;
        bool okr = rr < NB;
        mab[s][q] = (okr && cnt_ab[rr] > 0) ? 1.f : 0.f;
        mbb[s][q] = (okr && cnt_bb[rr] > 0) ? 1.f : 0.f;
      }
    }
    float* h = out + TOTA;
    float* cn = out + 2 * TOTA + TOTB;
    float bm1[4], bm2[4], bc[4];
    #pragma unroll
    for (int g = 0; g < 4; ++g) {
      bm1[g] = Bv[(g * 5 + 2) * 64 + col];
      bm2[g] = Bv[(g * 5 + 3) * 64 + col];
      bc[g]  = Bv[(g * 5 + 4) * 64 + col];
    }
    float cpre[2][4];
    #pragma unroll
    for (int s = 0; s < 2; ++s)
      #pragma unroll
      for (int q = 0; q < 4; ++q) {
        int rr = row0 + s * 16 + l4 * 4 + q;
        cpre[s][q] = (rr < NB) ? c_b[(size_t)rr * 64 + col] : 0.f;
      }
    f32x4 z[2][4];
    #pragma unroll
    for (int s = 0; s < 2; ++s)
      #pragma unroll
      for (int g = 0; g < 4; ++g) z[s][g] = (f32x4){0.f, 0.f, 0.f, 0.f};
    #pragma unroll
    for (int g = 0; g < 4; ++g) {
      bf16x8 fr[6];
      #pragma unroll
      for (int t = 0; t < 6; ++t) fr[t] = FRAG(12 + g * 6 + t, nt);
      #pragma unroll
      for (int s = 0; s < 2; ++s) {
        #pragma unroll
        for (int t = 0; t < 6; ++t)
          z[s][g] = __builtin_amdgcn_mfma_f32_16x16x32_bf16(a[t][s], fr[t], z[s][g], 0, 0, 0);
      }
    }
    #pragma unroll
    for (int s = 0; s < 2; ++s) {
      #pragma unroll
      for (int q = 0; q < 4; ++q) {
        int rr = row0 + s * 16 + l4 * 4 + q;
        if (rr >= NB) continue;
        float zi = z[s][0][q] + mab[s][q] * bm1[0] + mbb[s][q] * bm2[0] + bc[0];
        float zf = z[s][1][q] + mab[s][q] * bm1[1] + mbb[s][q] * bm2[1] + bc[1];
        float zo = z[s][2][q] + mab[s][q] * bm1[2] + mbb[s][q] * bm2[2] + bc[2];
        float zg = z[s][3][q] + mab[s][q] * bm1[3] + mbb[s][q] * bm2[3] + bc[3];
        float ig = fast_sigmoid(zi);
        float fg = fast_sigmoid(zf);
        float og = fast_sigmoid(zo);
        float gg = fast_tanh(zg);
        size_t idx = (size_t)rr * 64 + col;
        float cv = fg * cpre[s][q] + ig * gg;
        h[idx] = og * fast_tanh(cv);
        cn[idx] = cv;
      }
    }
  }
  #undef FRAG
}

extern "C" void kernel_launch(void* const* d_in, const int* in_sizes, int n_in,
                              void* d_out, int out_size, void* d_ws, size_t ws_size,
                              hipStream_t stream) {
  (void)in_sizes; (void)n_in; (void)out_size; (void)ws_size;
  const float* x_a    = (const float*)d_in[0];
  const float* x_b    = (const float*)d_in[1];
  const float* c_a    = (const float*)d_in[2];
  const float* c_b    = (const float*)d_in[3];
  const float* lin_w  = (const float*)d_in[4];
  const float* lin_b  = (const float*)d_in[5];
  const float* conv_wl = (const float*)d_in[6];
  const float* conv_wr = (const float*)d_in[7];
  const float* conv_cb = (const float*)d_in[8];
  const int* src_aa = (const int*)d_in[9];
  const int* dst_aa = (const int*)d_in[10];
  const int* src_ab = (const int*)d_in[11];
  const int* dst_ab = (const int*)d_in[12];
  const int* src_bb = (const int*)d_in[13];
  const int* dst_bb = (const int*)d_in[14];

  char* ws = (char*)d_ws;
  size_t off = 0;
  auto alloc = [&](size_t bytes) -> char* {
    off = (off + 255) & ~(size_t)255;
    char* p = ws + off;
    off += bytes;
    return p;
  };
  bf16* xab = (bf16*)alloc((size_t)NA * 32 * 2);
  bf16* xbb = (bf16*)alloc((size_t)NB * 32 * 2);
  bf16* P   = (bf16*)alloc((size_t)NA * 32 * 2);
  bf16* P2  = (bf16*)alloc((size_t)NA * 32 * 2);
  bf16* Q   = (bf16*)alloc((size_t)NB * 32 * 2);
  bf16* R   = (bf16*)alloc((size_t)NB * 32 * 2);
  bf16* Q2  = (bf16*)alloc((size_t)NB * 32 * 2);
  bf16* S   = (bf16*)alloc((size_t)NB * 32 * 2);
  bf16* T   = (bf16*)alloc((size_t)NB * 32 * 2);
  float* Mbuf = (float*)alloc((size_t)20 * 2048 * 4);
  bf16* Wfrag = (bf16*)alloc((size_t)36 * 4 * 64 * 8 * 2);
  float* Bv = (float*)alloc((size_t)4 * 5 * 64 * 4);
  int* col_aa  = (int*)alloc((size_t)EAA * 4);
  int* col_ab  = (int*)alloc((size_t)EAB * 4);
  int* col_bb  = (int*)alloc((size_t)EBB * 4);
  int* pk_aa   = (int*)alloc((size_t)EAA * 4);
  int* pk_ab   = (int*)alloc((size_t)EAB * 4);
  int* pk_bb   = (int*)alloc((size_t)EBB * 4);
  int* start_aa = (int*)alloc((size_t)NA * 4);
  int* start_ab = (int*)alloc((size_t)NB * 4);
  int* start_bb = (int*)alloc((size_t)NB * 4);
  int* cnt_aa  = (int*)alloc((size_t)NA * 4);
  int* cnt_ab  = (int*)alloc((size_t)NB * 4);
  int* cnt_bb  = (int*)alloc((size_t)NB * 4);
  int* binAA   = (int*)alloc((size_t)BKA * NBKAA * 4);
  int* binAB   = (int*)alloc((size_t)BKB * NBKB * 4);
  int* binBB   = (int*)alloc((size_t)BKB * NBKB * 4);
  int* totAA   = (int*)alloc((size_t)NBKAA * 4);
  int* totAB   = (int*)alloc((size_t)NBKB * 4);
  int* totBB   = (int*)alloc((size_t)NBKB * 4);
  int* bsAA    = (int*)alloc((size_t)(NBKAA + 1) * 4);
  int* bsAB    = (int*)alloc((size_t)(NBKB + 1) * 4);
  int* bsBB    = (int*)alloc((size_t)(NBKB + 1) * 4);

  // weight folding (parallelized) + x cast
  kW1<<<20, 256, 0, stream>>>(lin_w, conv_wl, conv_wr, Mbuf);
  kW2<<<40, 256, 0, stream>>>(Mbuf, conv_wl, conv_wr, conv_cb, lin_b, Wfrag, Bv);
  k_cast2<<<4688, 256, 0, stream>>>(x_a, x_b, xab, xbb);

  // atomic-free CSR build (counting sort)
  kA_bin<<<BKA + 2 * BKB, 256, 0, stream>>>(dst_aa, dst_ab, dst_bb, binAA, binAB, binBB);
  kB1<<<(NBKAA + 2 * NBKB) / 4, 256, 0, stream>>>(binAA, binAB, binBB, totAA, totAB, totBB);
  kB2<<<3, 256, 0, stream>>>(totAA, totAB, totBB, bsAA, bsAB, bsBB);
  kC_scatter<<<BKA + 2 * BKB, 256, 0, stream>>>(src_aa, dst_aa, src_ab, dst_ab, src_bb, dst_bb,
                                                binAA, binAB, binBB, bsAA, bsAB, bsBB,
                                                pk_aa, pk_ab, pk_bb);
  kD_nodesort<<<NBKAA + 2 * NBKB, 256, 0, stream>>>(pk_aa, pk_ab, pk_bb, bsAA, bsAB, bsBB,
                                                    col_aa, col_ab, col_bb,
                                                    start_aa, cnt_aa, start_ab, cnt_ab,
                                                    start_bb, cnt_bb);

  // aggregation chains (32-ch rows only)
  k_aggP1<<<50000, 256, 0, stream>>>(xab, xbb, P, Q, R,
                                     start_aa, cnt_aa, col_aa,
                                     start_ab, cnt_ab, col_ab,
                                     start_bb, cnt_bb, col_bb);
  k_aggP2<<<50000, 256, 0, stream>>>(P, Q, R, P2, Q2, S, T,
                                     start_aa, cnt_aa, col_aa,
                                     start_ab, cnt_ab, col_ab,
                                     start_bb, cnt_bb, col_bb);

  // fused z-matmul + LSTM: block = 32 rows, wave = nt quadrant
  k_fin<<<GF3A + GF3B, 256, 0, stream>>>(xab, P, P2, xbb, Q, R, Q2, S, T,
                                         Wfrag, Bv, cnt_aa, cnt_ab, cnt_bb,
                                         c_a, c_b, (float*)d_out);
}